// Round 3
// baseline (15.328 us; speedup 1.0000x reference)
//
#include <hip/hip_runtime.h>

// out[b,co,h,w] = max over ci of |x[b,ci,h,w] + w[co,ci]|
// B=8, CIN=COUT=64, H=W=56 -> HW=3136, spatial S = B*HW = 25088
//
// Thread = (2 consecutive spatial via float2, 4 co).
// Block  = 256 threads (4 waves) = 128 spatial x 16 co.
// Grid   = (25088/128 = 196 spatial chunks) x (4 co-quarters) = 784 blocks,
//          3136 waves (~3/SIMD, ~3 blocks/CU).
//
// 128-spatial chunks are NOT b-aligned (3136 % 128 != 0), so compute the
// per-lane fold: flat index into x/out is s + b*63*3136 (+ c*3136), where
// s = global spatial id and b = s/3136. Pairs (s, s+1) never straddle a b
// boundary since s is even and 3136 is even.

__global__ __launch_bounds__(256) void Conv1x1_53429393162852_kernel(
    const float* __restrict__ x, const float* __restrict__ w,
    float* __restrict__ out) {
  const int lane   = threadIdx.x & 63;
  const int wid    = threadIdx.x >> 6;            // 0..3
  const int schunk = blockIdx.x >> 2;             // 0..195
  const int coq    = blockIdx.x & 3;              // co-quarter fastest: L2 reuse
  const int s2     = schunk * 128 + lane * 2;     // even spatial index < 25088
  const int b      = s2 / 3136;                   // per-lane (chunks unaligned)
  const size_t base = (size_t)s2 + (size_t)b * (63 * 3136);

  // co base is wave-uniform -> SGPR -> weights come from the scalar cache.
  const int co0 = __builtin_amdgcn_readfirstlane(coq * 16 + wid * 4);

  const float* xp = x + base;
  const float* wp = w + co0 * 64;

  float accx[4] = {0.f, 0.f, 0.f, 0.f};           // spatial s2
  float accy[4] = {0.f, 0.f, 0.f, 0.f};           // spatial s2+1

#pragma unroll
  for (int ci = 0; ci < 64; ci += 2) {
    const float2 xv0 = *(const float2*)(xp + (size_t)ci * 3136);
    const float2 xv1 = *(const float2*)(xp + (size_t)(ci + 1) * 3136);
#pragma unroll
    for (int j = 0; j < 4; ++j) {
      const float w0 = wp[j * 64 + ci];
      const float w1 = wp[j * 64 + ci + 1];
      const float t0x = xv0.x + w0, t1x = xv1.x + w1;
      const float t0y = xv0.y + w0, t1y = xv1.y + w1;
      // acc = max(acc, |t0|, |t1|): one VOP3, abs() is a free input modifier.
      asm("v_max3_f32 %0, abs(%1), abs(%2), %0"
          : "+v"(accx[j]) : "v"(t0x), "v"(t1x));
      asm("v_max3_f32 %0, abs(%1), abs(%2), %0"
          : "+v"(accy[j]) : "v"(t0y), "v"(t1y));
    }
  }

  float* op = out + base;
#pragma unroll
  for (int j = 0; j < 4; ++j) {
    float2 r;
    r.x = accx[j];
    r.y = accy[j];
    *(float2*)(op + (size_t)(co0 + j) * 3136) = r;   // 512 B/wave coalesced
  }
}

extern "C" void kernel_launch(void* const* d_in, const int* in_sizes, int n_in,
                              void* d_out, int out_size, void* d_ws, size_t ws_size,
                              hipStream_t stream) {
  const float* x = (const float*)d_in[0];      // (8, 64, 56, 56) fp32
  const float* w = (const float*)d_in[1];      // (64, 64, 1, 1)  fp32
  float* out = (float*)d_out;                  // (8, 64, 56, 56) fp32

  dim3 grid(196 * 4), block(256);
  hipLaunchKernelGGL(Conv1x1_53429393162852_kernel, grid, block, 0, stream,
                     x, w, out);
}

// Round 4
// 13.590 us; speedup vs baseline: 1.1279x; 1.1279x over previous
//
#include <hip/hip_runtime.h>

// out[b,co,h,w] = max over ci of |x[b,ci,h,w] + w[co,ci]|
// B=8, CIN=COUT=64, H=W=56 -> HW=3136, spatial S = B*HW = 25088
//
// Round-1 geometry (best measured) + max3 inner loop:
//   Block = 512 threads (8 waves); lane -> spatial within a 64-chunk
//   (3136 % 64 == 0 so b is wave-uniform); wave w -> co [8w, 8w+8).
//   Grid = 25088/64 = 392 blocks. x-tile (16 KB) read once per block, all
//   64 co computed from it (max x-reuse, single kernel, minimal traffic).
// Inner loop: 2 ci/step, v_max3_f32 with free abs() input modifiers:
//   per thread 64 loads + 512 v_add + 256 v_max3 (vs round-1's 512 v_max).

__global__ __launch_bounds__(512) void Conv1x1_53429393162852_kernel(
    const float* __restrict__ x, const float* __restrict__ w,
    float* __restrict__ out) {
  const int lane = threadIdx.x & 63;
  const int wid  = threadIdx.x >> 6;              // 0..7
  const int s    = blockIdx.x * 64 + lane;        // spatial index < 25088
  const int b    = s / 3136;                      // wave-uniform
  const int hw   = s - b * 3136;
  // Wave-uniform co base -> SGPR -> weight reads come from the scalar cache.
  const int co0  = __builtin_amdgcn_readfirstlane(wid * 8);

  const float* xp = x + (size_t)b * 64 * 3136 + hw;
  const float* wp = w + co0 * 64;

  float acc[8];
#pragma unroll
  for (int j = 0; j < 8; ++j) acc[j] = 0.0f;      // |.| >= 0: safe floor

#pragma unroll
  for (int ci = 0; ci < 64; ci += 2) {
    const float xv0 = xp[(size_t)ci * 3136];
    const float xv1 = xp[(size_t)(ci + 1) * 3136];
#pragma unroll
    for (int j = 0; j < 8; ++j) {
      const float t0 = xv0 + wp[j * 64 + ci];     // v_add_f32 v, s, v
      const float t1 = xv1 + wp[j * 64 + ci + 1];
      // acc = max(acc, |t0|, |t1|): one VOP3 op, abs() is free.
      asm("v_max3_f32 %0, abs(%1), abs(%2), %0"
          : "+v"(acc[j]) : "v"(t0), "v"(t1));
    }
  }

  float* op = out + (size_t)b * 64 * 3136 + hw;
#pragma unroll
  for (int j = 0; j < 8; ++j) op[(size_t)(co0 + j) * 3136] = acc[j];
}

extern "C" void kernel_launch(void* const* d_in, const int* in_sizes, int n_in,
                              void* d_out, int out_size, void* d_ws, size_t ws_size,
                              hipStream_t stream) {
  const float* x = (const float*)d_in[0];      // (8, 64, 56, 56) fp32
  const float* w = (const float*)d_in[1];      // (64, 64, 1, 1)  fp32
  float* out = (float*)d_out;                  // (8, 64, 56, 56) fp32

  dim3 grid(392), block(512);
  hipLaunchKernelGGL(Conv1x1_53429393162852_kernel, grid, block, 0, stream,
                     x, w, out);
}